// Round 1
// baseline (1809.029 us; speedup 1.0000x reference)
//
#include <hip/hip_runtime.h>
#include <float.h>

#define NDIM 128
#define NHID 64
#define CHUNK 64
#define XSTR 68   // padded LDS row stride for xs (16B-aligned, bank-rotating)

__device__ __forceinline__ int bval(const int* __restrict__ b, int i, int is64) {
  return is64 ? b[2 * i] : b[i];
}

__global__ __launch_bounds__(256, 2)
void attn_pool_kernel(const float* __restrict__ x,
                      const int* __restrict__ braw,
                      const float* __restrict__ W1,
                      const float* __restrict__ b1,
                      const float* __restrict__ W2,
                      const float* __restrict__ b2,
                      float* __restrict__ out,
                      int n)
{
  __shared__ float w1s[NDIM * NHID];     // 32 KB, [k][h]
  __shared__ float xs[NDIM * XSTR];      // 34 KB, [k][p] transposed chunk
  __shared__ float ptl[16 * CHUNK];      // gate partial sums [hg][p]
  __shared__ float ebuf[CHUNK];
  __shared__ float accbuf[NDIM];
  __shared__ float b1s[NHID], w2s[NHID];
  __shared__ float s_m, s_denom, s_scale, s_b2;
  __shared__ int s_start, s_end;

  const int tid = threadIdx.x;
  const int g = blockIdx.x;

  // ---- stage W1 (coalesced float4), b1, W2 ----
  {
    const float4* src = (const float4*)W1;
    float4* dst = (float4*)w1s;
#pragma unroll
    for (int j = 0; j < 8; ++j) dst[tid + 256 * j] = src[tid + 256 * j];
  }
  if (tid >= 64 && tid < 128)  b1s[tid - 64]  = b1[tid - 64];
  if (tid >= 128 && tid < 192) w2s[tid - 128] = W2[tid - 128];
  if (tid == 0) {
    // detect int64 vs int32 batch layout: int64 -> high dwords are 0
    int jm = (n >> 1) & ~1;
    int is64 = (braw[jm] != 0 && braw[jm + 1] == 0) ? 1 : 0;
    // lower_bound(g)
    int lo = 0, hi = n;
    while (lo < hi) { int mid = (lo + hi) >> 1; if (bval(braw, mid, is64) < g) lo = mid + 1; else hi = mid; }
    s_start = lo;
    hi = n;
    while (lo < hi) { int mid = (lo + hi) >> 1; if (bval(braw, mid, is64) < g + 1) lo = mid + 1; else hi = mid; }
    s_end = lo;
    s_m = -FLT_MAX;
    s_denom = 0.f;
    s_b2 = b2[0];
  }
  __syncthreads();

  const int seg0 = s_start, seg1 = s_end;
  const int pg = tid & 15;        // point group (4 pts)
  const int hg = tid >> 4;        // hidden group (4 hid)
  const int down = tid & 127;     // owned output dim
  const int half = tid >> 7;      // which half of the 64 points to accumulate
  float accd = 0.f;               // running weighted sum for dim `down` (this half)

  for (int pos = seg0; pos < seg1; pos += CHUNK) {
    const int cnt = min(CHUNK, seg1 - pos);
    __syncthreads();  // xs safe to overwrite (prev chunk's readers done)

    // ---- stage x chunk, transposed into xs[k][p] ----
    {
      const int p = tid >> 2;
      const float4* xrow = (const float4*)(x + (size_t)(pos + p) * NDIM);
#pragma unroll
      for (int j = 0; j < 8; ++j) {
        const int f4 = (tid & 3) + 4 * j;
        float4 v = (p < cnt) ? xrow[f4] : make_float4(0.f, 0.f, 0.f, 0.f);
        const int k0 = f4 * 4;
        xs[(k0 + 0) * XSTR + p] = v.x;
        xs[(k0 + 1) * XSTR + p] = v.y;
        xs[(k0 + 2) * XSTR + p] = v.z;
        xs[(k0 + 3) * XSTR + p] = v.w;
      }
    }
    __syncthreads();

    // ---- gate GEMM: 4 points x 4 hidden per thread ----
    float acc[4][4] = {};
    {
      const float* xp = xs + pg * 4;
      const float* wp = w1s + hg * 4;
#pragma unroll 4
      for (int k = 0; k < NDIM; ++k) {
        const float4 xv = *(const float4*)(xp + k * XSTR);
        const float4 wv = *(const float4*)(wp + k * NHID);
        acc[0][0] += xv.x * wv.x; acc[0][1] += xv.x * wv.y; acc[0][2] += xv.x * wv.z; acc[0][3] += xv.x * wv.w;
        acc[1][0] += xv.y * wv.x; acc[1][1] += xv.y * wv.y; acc[1][2] += xv.y * wv.z; acc[1][3] += xv.y * wv.w;
        acc[2][0] += xv.z * wv.x; acc[2][1] += xv.z * wv.y; acc[2][2] += xv.z * wv.z; acc[2][3] += xv.z * wv.w;
        acc[3][0] += xv.w * wv.x; acc[3][1] += xv.w * wv.y; acc[3][2] += xv.w * wv.z; acc[3][3] += xv.w * wv.w;
      }
    }
    // relu + W2 partial dot per point
#pragma unroll
    for (int j = 0; j < 4; ++j) {
      float s = 0.f;
#pragma unroll
      for (int i = 0; i < 4; ++i) {
        const float h = fmaxf(acc[j][i] + b1s[hg * 4 + i], 0.f);
        s += h * w2s[hg * 4 + i];
      }
      ptl[hg * CHUNK + pg * 4 + j] = s;
    }
    __syncthreads();

    // ---- wave 0: finish gates, online-softmax state update ----
    if (tid < 64) {
      float gt = -FLT_MAX;
      if (tid < cnt) {
        gt = s_b2;
#pragma unroll
        for (int h = 0; h < 16; ++h) gt += ptl[h * CHUNK + tid];
      }
      float mc = gt;
#pragma unroll
      for (int o = 32; o > 0; o >>= 1) mc = fmaxf(mc, __shfl_xor(mc, o, 64));
      const float m_old = s_m;
      const float m_new = fmaxf(m_old, mc);
      const float e = (tid < cnt) ? __expf(gt - m_new) : 0.f;
      ebuf[tid] = e;
      float es = e;
#pragma unroll
      for (int o = 32; o > 0; o >>= 1) es += __shfl_xor(es, o, 64);
      if (tid == 0) {
        const float sc = __expf(m_old - m_new);
        s_scale = sc;
        s_denom = s_denom * sc + es;
        s_m = m_new;
      }
    }
    __syncthreads();

    // ---- rescale + accumulate weighted x from LDS ----
    {
      const float sc = s_scale;
      const float* xr = xs + down * XSTR + half * 32;
      const float* eb = ebuf + half * 32;
      float sum = 0.f;
#pragma unroll 8
      for (int p = 0; p < 32; ++p) sum += eb[p] * xr[p];
      accd = accd * sc + sum;
    }
  }

  // ---- epilogue: combine halves, normalize, write ----
  __syncthreads();
  if (half == 1) accbuf[down] = accd;
  __syncthreads();
  if (tid < 128) {
    const float den = s_denom;
    const float tot = accd + accbuf[tid];
    out[(size_t)g * NDIM + tid] = (seg1 > seg0) ? (tot / den) : 0.f;
  }
}

extern "C" void kernel_launch(void* const* d_in, const int* in_sizes, int n_in,
                              void* d_out, int out_size, void* d_ws, size_t ws_size,
                              hipStream_t stream) {
  const float* x  = (const float*)d_in[0];
  const int* braw = (const int*)d_in[1];
  const float* W1 = (const float*)d_in[2];
  const float* b1 = (const float*)d_in[3];
  const float* W2 = (const float*)d_in[4];
  const float* b2 = (const float*)d_in[5];
  float* out = (float*)d_out;
  const int n = in_sizes[1];                // number of points
  const int num_graphs = out_size / NDIM;   // 8192
  attn_pool_kernel<<<num_graphs, 256, 0, stream>>>(x, braw, W1, b1, W2, b2, out, n);
}